// Round 5
// baseline (855.378 us; speedup 1.0000x reference)
//
#include <hip/hip_runtime.h>

// ===========================================================================
// Frequency-domain block-circulant linear:
//   y[n, j*256+k] = irfft_f( rfft(c)[j,i,f] * rfft(x)[n,i,f] summed over i )
// Kernel 1 (cf_pre): CF[f][j][i] = sum_k c[j,i,k] e^{-2pi i k f/256}, f=0..128
// Kernel 2 (bcfft): per row n: fwd FFT-256 (16 blocks) -> freq GEMM -> inv FFT
// All f32. FFT-256 factored 16x16: m=16a+b, f=16c+d.
//   fwd:  Z_b[d] = sum_a x[16a+b] W16^{ad}   (W = e^{-2pi i /N})
//         X[16c+d] = sum_b (Z_b[d] W256^{bd}) W16^{bc}
//         computed for d=0..8, c=0..15; slots f>128 folded by conj into 256-f.
//   inv:  U_d[b] = sum_c Y[16c+d] conj(W16^{cb})   (d=0..8; Y[f>128]=conj(Y[256-f]))
//         V_d[b] = U_d[b] conj(W256^{db});  V_{16-d} = conj(V_d)
//         y[16a+b] = (ReV_0 + (-1)^a ReV_8 + 2 sum_{d=1..7} Re(W16^{-da} V_d))/256
// ===========================================================================

#define TWO_PI_256 0.0245436926f   // 2*pi/256

__global__ __launch_bounds__(256) void cf_pre(const float* __restrict__ c,
                                              float2* __restrict__ CF) {
    const int f = blockIdx.x;        // 0..128
    const int t = threadIdx.x;       // j*16 + i
    const float* cr = c + (size_t)t * 256;
    float ar = 0.f, ai = 0.f;
    for (int k = 0; k < 256; ++k) {
        float s, co;
        sincosf((float)((k * f) & 255) * TWO_PI_256, &s, &co);
        float v = cr[k];
        ar += v * co;
        ai -= v * s;
    }
    CF[(size_t)f * 256 + t] = make_float2(ar, ai);
}

__global__ __launch_bounds__(256, 2) void bcfft(const float* __restrict__ x,
                                                const float2* __restrict__ CF,
                                                const float* __restrict__ bias,
                                                float* __restrict__ y) {
    __shared__ float2 TW[256];            // TW[t] = (cos, -sin)(2 pi t/256)
    __shared__ float2 XY[4 * 129 * 16];   // per-wave row: [f][i] then in-place [f][j]

    const int tid = threadIdx.x;
    {
        float s, co;
        sincosf((float)tid * TWO_PI_256, &s, &co);
        TW[tid] = make_float2(co, -s);
    }
    __syncthreads();

    const int w  = tid >> 6;          // wave = row within block
    const int l  = tid & 63;
    const int q  = l & 3;             // quad position: owns b = 4q..4q+3
    const int ib = l >> 2;            // i-block 0..15
    const size_t n = (size_t)blockIdx.x * 4 + w;
    float2* XL = XY + w * (129 * 16);

    // ---------------- phase 1: forward FFT of row n ----------------
    {
        const float* xr = x + n * 4096 + ib * 256 + q * 4;
        float4 M[16];
#pragma unroll
        for (int a = 0; a < 16; ++a)
            M[a] = *(const float4*)(xr + a * 16);

        float Zr[4][9], Zi[4][9];
#pragma unroll
        for (int t = 0; t < 4; ++t)
#pragma unroll
            for (int d = 0; d < 9; ++d) { Zr[t][d] = 0.f; Zi[t][d] = 0.f; }

#pragma unroll
        for (int a = 0; a < 16; ++a) {
            const float* Ma = (const float*)&M[a];
#pragma unroll
            for (int d = 0; d < 9; ++d) {
                float2 tw = TW[(16 * a * d) & 255];
#pragma unroll
                for (int t = 0; t < 4; ++t) {
                    Zr[t][d] += Ma[t] * tw.x;
                    Zi[t][d] += Ma[t] * tw.y;
                }
            }
        }
        // twiddle: T = Z * W256^{b d},  b = 4q+t
#pragma unroll
        for (int t = 0; t < 4; ++t) {
            const int b = 4 * q + t;
#pragma unroll
            for (int d = 0; d < 9; ++d) {
                float2 tw = TW[b * d];          // <= 120, no mask needed
                float zr = Zr[t][d], zi = Zi[t][d];
                Zr[t][d] = zr * tw.x - zi * tw.y;
                Zi[t][d] = zr * tw.y + zi * tw.x;
            }
        }
        // outer DFT over b (quad-distributed) for c = 0..15
        for (int c = 0; c < 16; ++c) {
            float Pr[9], Pi[9];
#pragma unroll
            for (int d = 0; d < 9; ++d) { Pr[d] = 0.f; Pi[d] = 0.f; }
#pragma unroll
            for (int t = 0; t < 4; ++t) {
                const int b = 4 * q + t;
                float2 tw = TW[(16 * b * c) & 255];   // W16^{bc}
#pragma unroll
                for (int d = 0; d < 9; ++d) {
                    Pr[d] += Zr[t][d] * tw.x - Zi[t][d] * tw.y;
                    Pi[d] += Zr[t][d] * tw.y + Zi[t][d] * tw.x;
                }
            }
#pragma unroll
            for (int d = 0; d < 9; ++d) {
                Pr[d] += __shfl_xor(Pr[d], 1);
                Pi[d] += __shfl_xor(Pi[d], 1);
                Pr[d] += __shfl_xor(Pr[d], 2);
                Pi[d] += __shfl_xor(Pi[d], 2);
            }
            if ((c & 3) == q) {
#pragma unroll
                for (int d = 0; d < 9; ++d) {
                    if (d == 0 && c >= 9) continue;   // duplicate of direct res-0
                    if (d == 8 && c >= 8) continue;   // duplicate / f'=136
                    const int f = 16 * c + d;
                    if (f <= 128)
                        XL[f * 16 + ib] = make_float2(Pr[d], Pi[d]);
                    else
                        XL[(256 - f) * 16 + ib] = make_float2(Pr[d], -Pi[d]);
                }
            }
        }
    }
    __syncthreads();

    // ---------------- phase 2: freq GEMM, thread t <-> f = t ----------------
    if (tid < 129) {
        const int f = tid;
        float2 Xi[4][16];
#pragma unroll
        for (int r = 0; r < 4; ++r)
#pragma unroll
            for (int i = 0; i < 16; ++i)
                Xi[r][i] = XY[r * (129 * 16) + f * 16 + i];
        const float2* cf = CF + (size_t)f * 256;
        for (int j = 0; j < 16; ++j) {
            float2 Cj[16];
#pragma unroll
            for (int i = 0; i < 16; ++i) Cj[i] = cf[j * 16 + i];
#pragma unroll
            for (int r = 0; r < 4; ++r) {
                float yr = 0.f, yi = 0.f;
#pragma unroll
                for (int i = 0; i < 16; ++i) {
                    yr += Cj[i].x * Xi[r][i].x - Cj[i].y * Xi[r][i].y;
                    yi += Cj[i].x * Xi[r][i].y + Cj[i].y * Xi[r][i].x;
                }
                XY[r * (129 * 16) + f * 16 + j] = make_float2(yr, yi);
            }
        }
    }
    __syncthreads();

    // ---------------- phase 3: inverse FFT + bias + store ----------------
    {
        const int jb = ib;            // j-block for this lane
        float Ur[9][4], Ui[9][4];     // [d][t]
#pragma unroll
        for (int d = 0; d < 9; ++d)
#pragma unroll
            for (int t = 0; t < 4; ++t) { Ur[d][t] = 0.f; Ui[d][t] = 0.f; }

        for (int c = 0; c < 16; ++c) {
#pragma unroll
            for (int d = 0; d < 9; ++d) {
                const int fc = 16 * c + d;
                float2 yv;
                if (fc <= 128) {
                    yv = XL[fc * 16 + jb];
                } else {
                    yv = XL[(256 - fc) * 16 + jb];
                    yv.y = -yv.y;
                }
#pragma unroll
                for (int t = 0; t < 4; ++t) {
                    const int b = 4 * q + t;
                    float2 tw = TW[(16 * c * b) & 255];   // conj => e^{+2pi i cb/16}
                    Ur[d][t] += yv.x * tw.x + yv.y * tw.y;
                    Ui[d][t] += yv.y * tw.x - yv.x * tw.y;
                }
            }
        }
        // V_d = U_d * conj(W256^{d b})
#pragma unroll
        for (int d = 0; d < 9; ++d)
#pragma unroll
            for (int t = 0; t < 4; ++t) {
                const int b = 4 * q + t;
                float2 tw = TW[d * b];          // <= 120
                float ur = Ur[d][t], ui = Ui[d][t];
                Ur[d][t] = ur * tw.x + ui * tw.y;
                Ui[d][t] = ui * tw.x - ur * tw.y;
            }

        const float inv = 1.f / 256.f;
        float* yo = y + n * 4096 + jb * 256 + q * 4;
        const float* bo = bias + jb * 256 + q * 4;
#pragma unroll
        for (int a = 0; a < 16; ++a) {
            float4 o;
            float4 bv = *(const float4*)(bo + a * 16);
#pragma unroll
            for (int t = 0; t < 4; ++t) {
                float s = Ur[0][t] + ((a & 1) ? -Ur[8][t] : Ur[8][t]);
#pragma unroll
                for (int d = 1; d < 8; ++d) {
                    float2 tw = TW[(16 * d * a) & 255];   // (cos, -sin)(2pi da/16)
                    // Re(W16^{-da} V_d) = cos*Vr + sin*Vi = tw.x*Vr + (-tw.y)*... 
                    // W16^{-da} = (cos, +sin); Re = cos*Vr - sin*Vi_neg -> tw.x*Vr + tw.y*Vi? 
                    // derived: Re = tw.x*Ur - (-1)*...: using tw=(cos,-sin): Re = tw.x*Ur[d][t] + tw.y*Ui[d][t]
                    s += 2.f * (tw.x * Ur[d][t] + tw.y * Ui[d][t]);
                }
                ((float*)&o)[t] = s * inv + ((const float*)&bv)[t];
            }
            *(float4*)(yo + a * 16) = o;
        }
    }
}

// ---------------------------------------------------------------------------
extern "C" void kernel_launch(void* const* d_in, const int* in_sizes, int n_in,
                              void* d_out, int out_size, void* d_ws, size_t ws_size,
                              hipStream_t stream) {
    const float* x    = (const float*)d_in[0];   // (4,2048,4096) f32
    const float* c    = (const float*)d_in[1];   // (16,16,256) f32
    const float* bias = (const float*)d_in[2];   // (4096,) f32
    float* out = (float*)d_out;                  // (4,2048,4096) f32

    float2* CF = (float2*)d_ws;                  // 129*256 float2 = 264 KB

    hipLaunchKernelGGL(cf_pre, dim3(129), dim3(256), 0, stream, c, CF);
    hipLaunchKernelGGL(bcfft, dim3(2048), dim3(256), 0, stream,
                       x, CF, bias, out);
}

// Round 6
// 651.312 us; speedup vs baseline: 1.3133x; 1.3133x over previous
//
#include <hip/hip_runtime.h>

// ===========================================================================
// Frequency-domain block-circulant linear (math identical to the R5 kernel,
// which passed with absmax 0.0078):
//   y[n, j*256+k] = irfft_f( rfft(c)[j,i,f] * rfft(x)[n,i,f] summed over i )
// Mechanical fixes only:
//   - XY row stride padded 16 -> 17 float2 (kills 32-way bank conflict)
//   - phase 2: 258 subtasks (f, row-pair), all 256 threads active,
//     Xi[2][16] (64 VGPR) instead of Xi[4][16] (128 VGPR -> spilled)
//   - phase 1: M streamed (unroll 4) instead of 16 float4 held live
// ===========================================================================

#define TWO_PI_256 0.0245436926f   // 2*pi/256
#define FSTRIDE 17                 // padded float2 stride per frequency row
#define ROWSZ  (129 * FSTRIDE)     // per-data-row LDS float2 count

__global__ __launch_bounds__(256) void cf_pre(const float* __restrict__ c,
                                              float2* __restrict__ CF) {
    const int f = blockIdx.x;        // 0..128
    const int t = threadIdx.x;       // j*16 + i
    const float* cr = c + (size_t)t * 256;
    float ar = 0.f, ai = 0.f;
    for (int k = 0; k < 256; ++k) {
        float s, co;
        sincosf((float)((k * f) & 255) * TWO_PI_256, &s, &co);
        float v = cr[k];
        ar += v * co;
        ai -= v * s;
    }
    CF[(size_t)f * 256 + t] = make_float2(ar, ai);
}

__global__ __launch_bounds__(256, 2) void bcfft(const float* __restrict__ x,
                                                const float2* __restrict__ CF,
                                                const float* __restrict__ bias,
                                                float* __restrict__ y) {
    __shared__ float2 TW[256];        // TW[t] = (cos, -sin)(2 pi t/256)
    __shared__ float2 XY[4 * ROWSZ];  // per-wave row: [f][i] then in-place [f][j]

    const int tid = threadIdx.x;
    {
        float s, co;
        sincosf((float)tid * TWO_PI_256, &s, &co);
        TW[tid] = make_float2(co, -s);
    }
    __syncthreads();

    const int w  = tid >> 6;          // wave = data row within block
    const int l  = tid & 63;
    const int q  = l & 3;             // quad position: owns b = 4q..4q+3
    const int ib = l >> 2;            // i-block 0..15
    const size_t n = (size_t)blockIdx.x * 4 + w;
    float2* XL = XY + w * ROWSZ;

    // ---------------- phase 1: forward FFT of row n ----------------
    {
        const float* xr = x + n * 4096 + ib * 256 + q * 4;

        float Zr[4][9], Zi[4][9];
#pragma unroll
        for (int t = 0; t < 4; ++t)
#pragma unroll
            for (int d = 0; d < 9; ++d) { Zr[t][d] = 0.f; Zi[t][d] = 0.f; }

#pragma unroll 4
        for (int a = 0; a < 16; ++a) {
            float4 m = *(const float4*)(xr + a * 16);
            const float* Ma = (const float*)&m;
#pragma unroll
            for (int d = 0; d < 9; ++d) {
                float2 tw = TW[(16 * a * d) & 255];
#pragma unroll
                for (int t = 0; t < 4; ++t) {
                    Zr[t][d] += Ma[t] * tw.x;
                    Zi[t][d] += Ma[t] * tw.y;
                }
            }
        }
        // twiddle: T = Z * W256^{b d},  b = 4q+t
#pragma unroll
        for (int t = 0; t < 4; ++t) {
            const int b = 4 * q + t;
#pragma unroll
            for (int d = 0; d < 9; ++d) {
                float2 tw = TW[b * d];          // <= 120, no mask needed
                float zr = Zr[t][d], zi = Zi[t][d];
                Zr[t][d] = zr * tw.x - zi * tw.y;
                Zi[t][d] = zr * tw.y + zi * tw.x;
            }
        }
        // outer DFT over b (quad-distributed) for c = 0..15
        for (int c = 0; c < 16; ++c) {
            float Pr[9], Pi[9];
#pragma unroll
            for (int d = 0; d < 9; ++d) { Pr[d] = 0.f; Pi[d] = 0.f; }
#pragma unroll
            for (int t = 0; t < 4; ++t) {
                const int b = 4 * q + t;
                float2 tw = TW[(16 * b * c) & 255];   // W16^{bc}
#pragma unroll
                for (int d = 0; d < 9; ++d) {
                    Pr[d] += Zr[t][d] * tw.x - Zi[t][d] * tw.y;
                    Pi[d] += Zr[t][d] * tw.y + Zi[t][d] * tw.x;
                }
            }
#pragma unroll
            for (int d = 0; d < 9; ++d) {
                Pr[d] += __shfl_xor(Pr[d], 1);
                Pi[d] += __shfl_xor(Pi[d], 1);
                Pr[d] += __shfl_xor(Pr[d], 2);
                Pi[d] += __shfl_xor(Pi[d], 2);
            }
            if ((c & 3) == q) {
#pragma unroll
                for (int d = 0; d < 9; ++d) {
                    if (d == 0 && c >= 9) continue;   // duplicate of direct res-0
                    if (d == 8 && c >= 8) continue;   // duplicate / f'=136
                    const int f = 16 * c + d;
                    if (f <= 128)
                        XL[f * FSTRIDE + ib] = make_float2(Pr[d], Pi[d]);
                    else
                        XL[(256 - f) * FSTRIDE + ib] = make_float2(Pr[d], -Pi[d]);
                }
            }
        }
    }
    __syncthreads();

    // -------- phase 2: freq GEMM; 258 subtasks (f, row-pair) over 256 thr ----
    for (int s = tid; s < 258; s += 256) {
        const int f  = s >> 1;
        const int rp = s & 1;                 // rows 2rp, 2rp+1
        float2 Xi[2][16];
#pragma unroll
        for (int r = 0; r < 2; ++r)
#pragma unroll
            for (int i = 0; i < 16; ++i)
                Xi[r][i] = XY[(2 * rp + r) * ROWSZ + f * FSTRIDE + i];
        const float2* cf = CF + (size_t)f * 256;
        for (int j = 0; j < 16; ++j) {
            float2 Cj[16];
#pragma unroll
            for (int i = 0; i < 16; ++i) Cj[i] = cf[j * 16 + i];
#pragma unroll
            for (int r = 0; r < 2; ++r) {
                float yr = 0.f, yi = 0.f;
#pragma unroll
                for (int i = 0; i < 16; ++i) {
                    yr += Cj[i].x * Xi[r][i].x - Cj[i].y * Xi[r][i].y;
                    yi += Cj[i].x * Xi[r][i].y + Cj[i].y * Xi[r][i].x;
                }
                XY[(2 * rp + r) * ROWSZ + f * FSTRIDE + j] = make_float2(yr, yi);
            }
        }
    }
    __syncthreads();

    // ---------------- phase 3: inverse FFT + bias + store ----------------
    {
        const int jb = ib;            // j-block for this lane
        float Ur[9][4], Ui[9][4];     // [d][t]
#pragma unroll
        for (int d = 0; d < 9; ++d)
#pragma unroll
            for (int t = 0; t < 4; ++t) { Ur[d][t] = 0.f; Ui[d][t] = 0.f; }

        for (int c = 0; c < 16; ++c) {
#pragma unroll
            for (int d = 0; d < 9; ++d) {
                const int fc = 16 * c + d;
                float2 yv;
                if (fc <= 128) {
                    yv = XL[fc * FSTRIDE + jb];
                } else {
                    yv = XL[(256 - fc) * FSTRIDE + jb];
                    yv.y = -yv.y;
                }
#pragma unroll
                for (int t = 0; t < 4; ++t) {
                    const int b = 4 * q + t;
                    float2 tw = TW[(16 * c * b) & 255];   // conj => e^{+2pi i cb/16}
                    Ur[d][t] += yv.x * tw.x + yv.y * tw.y;
                    Ui[d][t] += yv.y * tw.x - yv.x * tw.y;
                }
            }
        }
        // V_d = U_d * conj(W256^{d b})
#pragma unroll
        for (int d = 0; d < 9; ++d)
#pragma unroll
            for (int t = 0; t < 4; ++t) {
                const int b = 4 * q + t;
                float2 tw = TW[d * b];          // <= 120
                float ur = Ur[d][t], ui = Ui[d][t];
                Ur[d][t] = ur * tw.x + ui * tw.y;
                Ui[d][t] = ui * tw.x - ur * tw.y;
            }

        const float inv = 1.f / 256.f;
        float* yo = y + n * 4096 + jb * 256 + q * 4;
        const float* bo = bias + jb * 256 + q * 4;
#pragma unroll
        for (int a = 0; a < 16; ++a) {
            float4 o;
            float4 bv = *(const float4*)(bo + a * 16);
#pragma unroll
            for (int t = 0; t < 4; ++t) {
                float s = Ur[0][t] + ((a & 1) ? -Ur[8][t] : Ur[8][t]);
#pragma unroll
                for (int d = 1; d < 8; ++d) {
                    // W16^{-da} = (cos th, +sin th), th = 2pi d a / 16;
                    // with tw = TW[16da] = (cos th, -sin th):
                    //   Re(W16^{-da} V_d) = tw.x*Vr + tw.y*Vi
                    float2 tw = TW[(16 * d * a) & 255];
                    s += 2.f * (tw.x * Ur[d][t] + tw.y * Ui[d][t]);
                }
                ((float*)&o)[t] = s * inv + ((const float*)&bv)[t];
            }
            *(float4*)(yo + a * 16) = o;
        }
    }
}

// ---------------------------------------------------------------------------
extern "C" void kernel_launch(void* const* d_in, const int* in_sizes, int n_in,
                              void* d_out, int out_size, void* d_ws, size_t ws_size,
                              hipStream_t stream) {
    const float* x    = (const float*)d_in[0];   // (4,2048,4096) f32
    const float* c    = (const float*)d_in[1];   // (16,16,256) f32
    const float* bias = (const float*)d_in[2];   // (4096,) f32
    float* out = (float*)d_out;                  // (4,2048,4096) f32

    float2* CF = (float2*)d_ws;                  // 129*256 float2 = 264 KB

    hipLaunchKernelGGL(cf_pre, dim3(129), dim3(256), 0, stream, c, CF);
    hipLaunchKernelGGL(bcfft, dim3(2048), dim3(256), 0, stream,
                       x, CF, bias, out);
}

// Round 7
// 487.003 us; speedup vs baseline: 1.7564x; 1.3374x over previous
//
#include <hip/hip_runtime.h>

// ===========================================================================
// Frequency-domain block-circulant linear (math identical to R5/R6 kernels,
// both passed with absmax 0.0078):
//   y[n, j*256+k] = irfft_f( rfft(c)[j,i,f] * rfft(x)[n,i,f] summed over i )
// R7 mechanical deltas only:
//   - launch_bounds(256) + amdgpu_waves_per_eu(1,2): stop the 128-VGPR
//     squeeze (LDS caps us at 2 blocks/CU anyway) -> kill scratch spills
//   - f32x4 ext_vector locals with static subscripts (SROA-proof)
//   - TW16 mini-table for W16 twiddles (old TW[(16uv)&255] reads all hit
//     LDS bank 0 -> 4-way serialization in the hot c-loops)
// ===========================================================================

typedef __attribute__((ext_vector_type(4))) float f32x4;

#define TWO_PI_256 0.0245436926f   // 2*pi/256
#define TWO_PI_16  0.392699082f    // 2*pi/16
#define FSTRIDE 17                 // padded float2 stride per frequency row
#define ROWSZ  (129 * FSTRIDE)     // per-data-row LDS float2 count

__global__ __launch_bounds__(256) void cf_pre(const float* __restrict__ c,
                                              float2* __restrict__ CF) {
    const int f = blockIdx.x;        // 0..128
    const int t = threadIdx.x;       // j*16 + i
    const float* cr = c + (size_t)t * 256;
    float ar = 0.f, ai = 0.f;
    for (int k = 0; k < 256; ++k) {
        float s, co;
        sincosf((float)((k * f) & 255) * TWO_PI_256, &s, &co);
        float v = cr[k];
        ar += v * co;
        ai -= v * s;
    }
    CF[(size_t)f * 256 + t] = make_float2(ar, ai);
}

__global__ __launch_bounds__(256) __attribute__((amdgpu_waves_per_eu(1, 2)))
void bcfft(const float* __restrict__ x,
           const float2* __restrict__ CF,
           const float* __restrict__ bias,
           float* __restrict__ y) {
    __shared__ float2 TW[256];        // TW[t]   = (cos, -sin)(2 pi t/256)
    __shared__ float2 TW16[16];       // TW16[t] = (cos, -sin)(2 pi t/16)
    __shared__ float2 XY[4 * ROWSZ];  // per-wave row: [f][i] then in-place [f][j]

    const int tid = threadIdx.x;
    {
        float s, co;
        sincosf((float)tid * TWO_PI_256, &s, &co);
        TW[tid] = make_float2(co, -s);
        if (tid < 16) {
            float s6, c6;
            sincosf((float)tid * TWO_PI_16, &s6, &c6);
            TW16[tid] = make_float2(c6, -s6);
        }
    }
    __syncthreads();

    const int w  = tid >> 6;          // wave = data row within block
    const int l  = tid & 63;
    const int q  = l & 3;             // quad position: owns b = 4q..4q+3
    const int ib = l >> 2;            // i-block 0..15
    const size_t n = (size_t)blockIdx.x * 4 + w;
    float2* XL = XY + w * ROWSZ;

    // ---------------- phase 1: forward FFT of row n ----------------
    {
        const float* xr = x + n * 4096 + ib * 256 + q * 4;

        float Zr[4][9], Zi[4][9];
#pragma unroll
        for (int t = 0; t < 4; ++t)
#pragma unroll
            for (int d = 0; d < 9; ++d) { Zr[t][d] = 0.f; Zi[t][d] = 0.f; }

#pragma unroll 4
        for (int a = 0; a < 16; ++a) {
            f32x4 m = *(const f32x4*)(xr + a * 16);
#pragma unroll
            for (int d = 0; d < 9; ++d) {
                float2 tw = TW16[(a * d) & 15];   // W16^{ad}
#pragma unroll
                for (int t = 0; t < 4; ++t) {
                    Zr[t][d] += m[t] * tw.x;
                    Zi[t][d] += m[t] * tw.y;
                }
            }
        }
        // twiddle: T = Z * W256^{b d},  b = 4q+t
#pragma unroll
        for (int t = 0; t < 4; ++t) {
            const int b = 4 * q + t;
#pragma unroll
            for (int d = 0; d < 9; ++d) {
                float2 tw = TW[b * d];          // <= 120, no mask needed
                float zr = Zr[t][d], zi = Zi[t][d];
                Zr[t][d] = zr * tw.x - zi * tw.y;
                Zi[t][d] = zr * tw.y + zi * tw.x;
            }
        }
        // outer DFT over b (quad-distributed) for c = 0..15
        for (int c = 0; c < 16; ++c) {
            float Pr[9], Pi[9];
#pragma unroll
            for (int d = 0; d < 9; ++d) { Pr[d] = 0.f; Pi[d] = 0.f; }
#pragma unroll
            for (int t = 0; t < 4; ++t) {
                const int b = 4 * q + t;
                float2 tw = TW16[(b * c) & 15];   // W16^{bc}
#pragma unroll
                for (int d = 0; d < 9; ++d) {
                    Pr[d] += Zr[t][d] * tw.x - Zi[t][d] * tw.y;
                    Pi[d] += Zr[t][d] * tw.y + Zi[t][d] * tw.x;
                }
            }
#pragma unroll
            for (int d = 0; d < 9; ++d) {
                Pr[d] += __shfl_xor(Pr[d], 1);
                Pi[d] += __shfl_xor(Pi[d], 1);
                Pr[d] += __shfl_xor(Pr[d], 2);
                Pi[d] += __shfl_xor(Pi[d], 2);
            }
            if ((c & 3) == q) {
#pragma unroll
                for (int d = 0; d < 9; ++d) {
                    if (d == 0 && c >= 9) continue;   // duplicate of direct res-0
                    if (d == 8 && c >= 8) continue;   // duplicate / f'=136
                    const int f = 16 * c + d;
                    if (f <= 128)
                        XL[f * FSTRIDE + ib] = make_float2(Pr[d], Pi[d]);
                    else
                        XL[(256 - f) * FSTRIDE + ib] = make_float2(Pr[d], -Pi[d]);
                }
            }
        }
    }
    __syncthreads();

    // -------- phase 2: freq GEMM; 258 subtasks (f, row-pair) over 256 thr ----
    for (int s = tid; s < 258; s += 256) {
        const int f  = s >> 1;
        const int rp = s & 1;                 // rows 2rp, 2rp+1
        float2 Xi[2][16];
#pragma unroll
        for (int r = 0; r < 2; ++r)
#pragma unroll
            for (int i = 0; i < 16; ++i)
                Xi[r][i] = XY[(2 * rp + r) * ROWSZ + f * FSTRIDE + i];
        const float2* cf = CF + (size_t)f * 256;
#pragma unroll 2
        for (int j = 0; j < 16; ++j) {
            float2 Cj[16];
#pragma unroll
            for (int i = 0; i < 16; ++i) Cj[i] = cf[j * 16 + i];
#pragma unroll
            for (int r = 0; r < 2; ++r) {
                float yr = 0.f, yi = 0.f;
#pragma unroll
                for (int i = 0; i < 16; ++i) {
                    yr += Cj[i].x * Xi[r][i].x - Cj[i].y * Xi[r][i].y;
                    yi += Cj[i].x * Xi[r][i].y + Cj[i].y * Xi[r][i].x;
                }
                XY[(2 * rp + r) * ROWSZ + f * FSTRIDE + j] = make_float2(yr, yi);
            }
        }
    }
    __syncthreads();

    // ---------------- phase 3: inverse FFT + bias + store ----------------
    {
        const int jb = ib;            // j-block for this lane
        float Ur[9][4], Ui[9][4];     // [d][t]
#pragma unroll
        for (int d = 0; d < 9; ++d)
#pragma unroll
            for (int t = 0; t < 4; ++t) { Ur[d][t] = 0.f; Ui[d][t] = 0.f; }

        for (int c = 0; c < 16; ++c) {
#pragma unroll
            for (int d = 0; d < 9; ++d) {
                const int fc = 16 * c + d;
                float2 yv;
                if (fc <= 128) {
                    yv = XL[fc * FSTRIDE + jb];
                } else {
                    yv = XL[(256 - fc) * FSTRIDE + jb];
                    yv.y = -yv.y;
                }
#pragma unroll
                for (int t = 0; t < 4; ++t) {
                    const int b = 4 * q + t;
                    float2 tw = TW16[(c * b) & 15];   // conj => e^{+2pi i cb/16}
                    Ur[d][t] += yv.x * tw.x + yv.y * tw.y;
                    Ui[d][t] += yv.y * tw.x - yv.x * tw.y;
                }
            }
        }
        // V_d = U_d * conj(W256^{d b})
#pragma unroll
        for (int d = 0; d < 9; ++d)
#pragma unroll
            for (int t = 0; t < 4; ++t) {
                const int b = 4 * q + t;
                float2 tw = TW[d * b];          // <= 120
                float ur = Ur[d][t], ui = Ui[d][t];
                Ur[d][t] = ur * tw.x + ui * tw.y;
                Ui[d][t] = ui * tw.x - ur * tw.y;
            }

        const float inv = 1.f / 256.f;
        float* yo = y + n * 4096 + jb * 256 + q * 4;
        const float* bo = bias + jb * 256 + q * 4;
#pragma unroll
        for (int a = 0; a < 16; ++a) {
            f32x4 o;
            f32x4 bv = *(const f32x4*)(bo + a * 16);
#pragma unroll
            for (int t = 0; t < 4; ++t) {
                float s = Ur[0][t] + ((a & 1) ? -Ur[8][t] : Ur[8][t]);
#pragma unroll
                for (int d = 1; d < 8; ++d) {
                    // W16^{-da} = (cos th, +sin th), th = 2pi d a/16; with
                    // tw = TW16[da] = (cos th, -sin th):
                    //   Re(W16^{-da} V_d) = tw.x*Vr + tw.y*Vi
                    float2 tw = TW16[(d * a) & 15];
                    s += 2.f * (tw.x * Ur[d][t] + tw.y * Ui[d][t]);
                }
                o[t] = s * inv + bv[t];
            }
            *(f32x4*)(yo + a * 16) = o;
        }
    }
}

// ---------------------------------------------------------------------------
extern "C" void kernel_launch(void* const* d_in, const int* in_sizes, int n_in,
                              void* d_out, int out_size, void* d_ws, size_t ws_size,
                              hipStream_t stream) {
    const float* x    = (const float*)d_in[0];   // (4,2048,4096) f32
    const float* c    = (const float*)d_in[1];   // (16,16,256) f32
    const float* bias = (const float*)d_in[2];   // (4096,) f32
    float* out = (float*)d_out;                  // (4,2048,4096) f32

    float2* CF = (float2*)d_ws;                  // 129*256 float2 = 264 KB

    hipLaunchKernelGGL(cf_pre, dim3(129), dim3(256), 0, stream, c, CF);
    hipLaunchKernelGGL(bcfft, dim3(2048), dim3(256), 0, stream,
                       x, CF, bias, out);
}

// Round 8
// 270.877 us; speedup vs baseline: 3.1578x; 1.7979x over previous
//
#include <hip/hip_runtime.h>

typedef unsigned int uint;
typedef unsigned short ushort;
typedef __attribute__((ext_vector_type(8))) short  short8;   // 8 bf16 (4 VGPRs)
typedef __attribute__((ext_vector_type(8))) unsigned short u16x8;
typedef __attribute__((ext_vector_type(4))) float  f32x4;    // MFMA accumulator

// round-to-nearest-even f32 -> bf16
__device__ __forceinline__ ushort f2b(float f) {
    uint u = __float_as_uint(f);
    u += 0x7FFFu + ((u >> 16) & 1u);
    return (ushort)(u >> 16);
}

__device__ __forceinline__ void async16(const void* g, void* l) {
    __builtin_amdgcn_global_load_lds(
        (const __attribute__((address_space(1))) void*)g,
        (__attribute__((address_space(3))) void*)l,
        16, 0, 0);
}

// ---------------------------------------------------------------------------
// Kernel 1: expand c (16,16,256) f32 -> Wt bf16 [N=4096][K=4096]
//   Wt[j*256+k][i*256+m] = c[j,i,(k-m)&255]
// ---------------------------------------------------------------------------
__global__ __launch_bounds__(256) void expand_w(const float* __restrict__ c,
                                                ushort* __restrict__ Wt) {
    const int j = blockIdx.x >> 4;
    const int i = blockIdx.x & 15;
    __shared__ ushort crev2[512];
    const float* cs = c + (size_t)(j * 16 + i) * 256;
    const int t = threadIdx.x;
    {
        ushort b = f2b(cs[(256 - t) & 255]);
        crev2[t] = b;
        crev2[t + 256] = b;
    }
    __syncthreads();
    const int tr = t >> 5;
    const int tm = (t & 31) * 8;
    for (int rb = 0; rb < 256; rb += 8) {
        const int k = rb + tr;
        u16x8 v;
#pragma unroll
        for (int u = 0; u < 8; ++u) v[u] = crev2[tm + u - k + 256];
        *(u16x8*)&Wt[(size_t)(j * 256 + k) * 4096 + i * 256 + tm] = v;
    }
}

// ---------------------------------------------------------------------------
// Kernel 2: x f32 -> bf16
// ---------------------------------------------------------------------------
__global__ __launch_bounds__(256) void conv_x(const float4* __restrict__ x,
                                              u16x8* __restrict__ xb, int n8) {
    int idx = blockIdx.x * blockDim.x + threadIdx.x;
    const int stride = gridDim.x * blockDim.x;
    for (; idx < n8; idx += stride) {
        float4 a = x[idx * 2];
        float4 b = x[idx * 2 + 1];
        u16x8 o;
        o[0] = f2b(a.x); o[1] = f2b(a.y); o[2] = f2b(a.z); o[3] = f2b(a.w);
        o[4] = f2b(b.x); o[5] = f2b(b.y); o[6] = f2b(b.z); o[7] = f2b(b.w);
        xb[idx] = o;
    }
}

// ---------------------------------------------------------------------------
// Kernel 3: 256x256-tile 8-phase GEMM (T1+T2+T3+T4+T5), even ds_read spread
//   C[8192][4096] = A[8192][4096] * Bt[4096][4096]^T + bias
// 512 thr = 8 waves (2M x 4N), per-wave 128x64. BK=64, 2 K-tiles/iter.
// LDS 128 KiB: 2 bufs x 4 slots(A0,A1,B0,B1) x [128][64] bf16.
// T2 swizzle (3-bit): 16B-slot s' = s ^ (row&7); inverse on GLOBAL source
// (linear gload_lds dest) + same XOR on ds_read col. 0-conflict (R3-verified).
// R8 delta vs R3: quadrants 2m x 4n; ds_reads 12/4/4/4 per K-tile (was
// 16/0/8/0) so each phase's lgkmcnt(0) drains <=12 (mostly 4) b128 reads.
// ---------------------------------------------------------------------------
#define BAR()   __builtin_amdgcn_s_barrier()
#define LGKM0() asm volatile("s_waitcnt lgkmcnt(0)" ::: "memory")
#define VMC6()  asm volatile("s_waitcnt vmcnt(6)" ::: "memory")
#define VMC0()  asm volatile("s_waitcnt vmcnt(0)" ::: "memory")
#define PRIO1() __builtin_amdgcn_s_setprio(1)
#define PRIO0() __builtin_amdgcn_s_setprio(0)

__global__ __launch_bounds__(512, 2) void gemm256(const ushort* __restrict__ A,
                                                  const ushort* __restrict__ Bt,
                                                  const float* __restrict__ bias,
                                                  float* __restrict__ C) {
    constexpr int K = 4096, N = 4096;
    __shared__ __align__(16) ushort lds[65536];  // 128 KiB

    const int tid  = threadIdx.x;
    const int wave = tid >> 6;
    const int lane = tid & 63;
    const int wr   = wave >> 2;       // 0..1
    const int wc   = wave & 3;        // 0..3
    const int lrow = lane & 15;
    const int kgrp = lane >> 4;

    // T1: XCD 8x8-square swizzle
    const int wg  = (int)blockIdx.x;
    const int xcd = wg & 7;
    const int idx = wg >> 3;
    const int bm  = (xcd & 3) * 8 + (idx & 7);   // 32 M-tiles
    const int bn  = (xcd >> 2) * 8 + (idx >> 3); // 16 N-tiles

    // staging: thread t covers linear LDS bytes [t*16,t*16+16) (+8KiB) of a
    // 16 KiB half-tile; source col carries the inverse swizzle
    const int r0  = tid >> 3;                              // 0..63
    const int cst = ((tid & 7) << 3) ^ ((r0 & 7) << 3);    // elem col, pre-swz
    const ushort* gA  = A  + (size_t)(bm * 256 + r0) * K + cst;
    const ushort* gB  = Bt + (size_t)(bn * 256 + r0) * K + cst;
    const ushort* gA2 = gA + (size_t)128 * K;
    const ushort* gB2 = gB + (size_t)128 * K;
    const size_t r64 = (size_t)64 * K;

#define STAGE(buf, slot, src, kt) do {                          \
        ushort* d_ = &lds[(buf) * 32768 + (slot) * 8192 + tid * 8]; \
        async16((src) + (kt), d_);                              \
        async16((src) + r64 + (kt), d_ + 4096);                 \
    } while (0)

    const int swz = (lrow & 7) << 3;   // 3-bit read swizzle (elems)

    f32x4 acc[8][4];
#pragma unroll
    for (int m = 0; m < 8; ++m)
#pragma unroll
        for (int n = 0; n < 4; ++n) acc[m][n] = (f32x4){0.f, 0.f, 0.f, 0.f};

    short8 af[2][2], bf[4][2];

    // LDAq(base, qm): A fragments for m-frags {2qm, 2qm+1} (4 x ds_read_b128)
    auto LDAq = [&](int base, int qm) {
#pragma unroll
        for (int m = 0; m < 2; ++m) {
            const int mf = 2 * qm + m;
#pragma unroll
            for (int ks = 0; ks < 2; ++ks)
                af[m][ks] = *(const short8*)&lds[base + wr * 8192 +
                                                 (mf >> 2) * 4096 +
                                                 (mf & 3) * 1024 + lrow * 64 +
                                                 ((ks * 32 + kgrp * 8) ^ swz)];
        }
    };
    // LDB(base): all 4 n fragments (8 x ds_read_b128)
    auto LDB = [&](int base) {
#pragma unroll
        for (int n = 0; n < 4; ++n)
#pragma unroll
            for (int ks = 0; ks < 2; ++ks)
                bf[n][ks] = *(const short8*)&lds[base + (2 + (wc >> 1)) * 8192 +
                                                 (wc & 1) * 4096 +
                                                 n * 1024 + lrow * 64 +
                                                 ((ks * 32 + kgrp * 8) ^ swz)];
    };

#define MMQ(QM) do {                                                         \
        _Pragma("unroll")                                                    \
        for (int m_ = 0; m_ < 2; ++m_)                                       \
            _Pragma("unroll")                                                \
            for (int n_ = 0; n_ < 4; ++n_)                                   \
                _Pragma("unroll")                                            \
                for (int ks_ = 0; ks_ < 2; ++ks_)                            \
                    acc[2 * (QM) + m_][n_] =                                 \
                        __builtin_amdgcn_mfma_f32_16x16x32_bf16(             \
                            af[m_][ks_], bf[n_][ks_],                        \
                            acc[2 * (QM) + m_][n_], 0, 0, 0);                \
    } while (0)

    // prologue: tile0 (buf0) fully + tile1 (buf1) 3 of 4 halves; order B0,B1,A0,A1
    STAGE(0, 2, gB, 0);  STAGE(0, 3, gB2, 0);  STAGE(0, 0, gA, 0);  STAGE(0, 1, gA2, 0);
    STAGE(1, 2, gB, 64); STAGE(1, 3, gB2, 64); STAGE(1, 0, gA, 64);
    VMC6();   // 14 issued, wait 8 oldest (= all of tile0)
    BAR();

    for (int it = 0; it < 31; ++it) {
        const int kt2 = it * 128 + 128, kt3 = kt2 + 64, ktn = kt2 - 64;
        // ---- tile t (buf0) ----
        // PH1: read B all + A m01; stage t+1's A1 (last half of t+1)
        LDB(0); LDAq(0, 0);
        STAGE(1, 1, gA2, ktn);
        BAR(); LGKM0(); PRIO1(); MMQ(0); PRIO0(); BAR();
        // PH2: read A m23; stage t+2 B0 (bf lives in regs)
        LDAq(0, 1);
        STAGE(0, 2, gB, kt2);
        BAR(); LGKM0(); PRIO1(); MMQ(1); PRIO0(); BAR();
        // PH3: read A m45; stage t+2 B1
        LDAq(0, 2);
        STAGE(0, 3, gB2, kt2);
        BAR(); LGKM0(); PRIO1(); MMQ(2); PRIO0(); BAR();
        // PH4: read A m67; stage t+2 A0; counted vmcnt -> tile t+1 landed
        LDAq(0, 3);
        STAGE(0, 0, gA, kt2);
        VMC6();
        BAR(); LGKM0(); PRIO1(); MMQ(3); PRIO0(); BAR();
        // ---- tile t+1 (buf1) ----
        // PH5: read B all + A m01; stage t+2 A1
        LDB(32768); LDAq(32768, 0);
        STAGE(0, 1, gA2, kt2);
        BAR(); LGKM0(); PRIO1(); MMQ(0); PRIO0(); BAR();
        // PH6: read A m23; stage t+3 B0
        LDAq(32768, 1);
        STAGE(1, 2, gB, kt3);
        BAR(); LGKM0(); PRIO1(); MMQ(1); PRIO0(); BAR();
        // PH7: read A m45; stage t+3 B1
        LDAq(32768, 2);
        STAGE(1, 3, gB2, kt3);
        BAR(); LGKM0(); PRIO1(); MMQ(2); PRIO0(); BAR();
        // PH8: read A m67; stage t+3 A0; counted vmcnt -> tile t+2 landed
        LDAq(32768, 3);
        STAGE(1, 0, gA, kt3);
        VMC6();
        BAR(); LGKM0(); PRIO1(); MMQ(3); PRIO0(); BAR();
    }

    // final iteration: tiles 62 (buf0, kt=3968) and 63 (buf1, kt=4032)
    {
        LDB(0); LDAq(0, 0);
        STAGE(1, 1, gA2, 4032);      // last half of tile 63
        BAR(); LGKM0(); PRIO1(); MMQ(0); PRIO0(); BAR();
        LDAq(0, 1);
        BAR(); LGKM0(); PRIO1(); MMQ(1); PRIO0(); BAR();
        LDAq(0, 2);
        BAR(); LGKM0(); PRIO1(); MMQ(2); PRIO0(); BAR();
        LDAq(0, 3);
        VMC0();                       // drain: tile 63 fully landed
        BAR(); LGKM0(); PRIO1(); MMQ(3); PRIO0(); BAR();
        // tile 63 (buf1): registers only, per-wave ordering suffices
        LDB(32768); LDAq(32768, 0);
        LGKM0(); PRIO1(); MMQ(0); PRIO0();
        LDAq(32768, 1);
        LGKM0(); PRIO1(); MMQ(1); PRIO0();
        LDAq(32768, 2);
        LGKM0(); PRIO1(); MMQ(2); PRIO0();
        LDAq(32768, 3);
        LGKM0(); PRIO1(); MMQ(3); PRIO0();
    }

    // epilogue: D row = kgrp*4 + reg, col = lrow (verified m89 layout)
    const int colbase = bn * 256 + wc * 64 + lrow;
    float bv[4];
#pragma unroll
    for (int n = 0; n < 4; ++n) bv[n] = bias[colbase + n * 16];
    const int rowbase = bm * 256 + wr * 128 + kgrp * 4;
#pragma unroll
    for (int m = 0; m < 8; ++m)
#pragma unroll
        for (int n = 0; n < 4; ++n) {
            const size_t base = (size_t)(rowbase + m * 16) * N + colbase + n * 16;
#pragma unroll
            for (int r = 0; r < 4; ++r)
                C[base + (size_t)r * N] = acc[m][n][r] + bv[n];
        }
#undef STAGE
#undef MMQ
}

// ---------------------------------------------------------------------------
extern "C" void kernel_launch(void* const* d_in, const int* in_sizes, int n_in,
                              void* d_out, int out_size, void* d_ws, size_t ws_size,
                              hipStream_t stream) {
    const float* x    = (const float*)d_in[0];   // (4,2048,4096) f32
    const float* c    = (const float*)d_in[1];   // (16,16,256) f32
    const float* bias = (const float*)d_in[2];   // (4096,) f32
    float* out = (float*)d_out;                  // (4,2048,4096) f32

    ushort* Wb = (ushort*)d_ws;                  // 32 MiB
    ushort* Xb = Wb + (size_t)4096 * 4096;       // 64 MiB

    hipLaunchKernelGGL(expand_w, dim3(256), dim3(256), 0, stream, c, Wb);
    hipLaunchKernelGGL(conv_x, dim3(2048), dim3(256), 0, stream,
                       (const float4*)x, (u16x8*)Xb, 33554432 / 8);
    hipLaunchKernelGGL(gemm256, dim3(512), dim3(512), 0, stream,
                       Xb, Wb, bias, out);
}